// Round 13
// baseline (883.424 us; speedup 1.0000x reference)
//
#include <hip/hip_runtime.h>
#include <math.h>

#define LN2PI 1.83787706640934548356f

// ---------------------------------------------------------------------------
// stem: conv 5x5 stride 2 valid + bias + relu : (16,2,32,32) -> (16,32,14,14)
// ---------------------------------------------------------------------------
__global__ void k_stem(const float* __restrict__ x, const float* __restrict__ w,
                       const float* __restrict__ bias, float* __restrict__ fea) {
    int idx = blockIdx.x * blockDim.x + threadIdx.x;
    if (idx >= 16*32*14*14) return;
    int ox = idx % 14, oy = (idx/14) % 14, oc = (idx/196) % 32, b = idx/(196*32);
    float s = bias[oc];
    const float* xb = x + b*2*1024;
    const float* wc = w + oc*2*25;
    #pragma unroll
    for (int ic = 0; ic < 2; ++ic)
        #pragma unroll
        for (int ky = 0; ky < 5; ++ky)
            #pragma unroll
            for (int kx = 0; kx < 5; ++kx)
                s = fmaf(xb[ic*1024 + (oy*2+ky)*32 + (ox*2+kx)],
                         wc[ic*25 + ky*5 + kx], s);
    fea[idx] = fmaxf(s, 0.f);
}

// ---------------------------------------------------------------------------
// primary caps
// ---------------------------------------------------------------------------
__global__ void k_primary(const float* __restrict__ fea,
                          const float* __restrict__ pw, const float* __restrict__ pb,
                          const float* __restrict__ aw, const float* __restrict__ ab,
                          float* __restrict__ M, float* __restrict__ a) {
    int idx = blockIdx.x * blockDim.x + threadIdx.x;
    if (idx >= 16*544*196) return;
    int hw = idx % 196, o = (idx/196) % 544, b = idx/(196*544);
    const float* f = fea + b*32*196 + hw;
    if (o < 512) {
        float s = pb[o];
        #pragma unroll
        for (int c = 0; c < 32; ++c) s = fmaf(f[c*196], pw[o*32+c], s);
        M[(b*512+o)*196 + hw] = s;
    } else {
        int oo = o - 512;
        float s = ab[oo];
        #pragma unroll
        for (int c = 0; c < 32; ++c) s = fmaf(f[c*196], aw[oo*32+c], s);
        a[(b*32+oo)*196 + hw] = 1.f/(1.f + __expf(-s));
    }
}

// ---------------------------------------------------------------------------
// patch extraction, m4-interleaved: aP[(b*P+p)*NI + i],
// MpV[((b*P+p)*4 + m4)*NI + i] = float4 of pose rows (coalesced per-lane-i)
// ---------------------------------------------------------------------------
__global__ void k_patch(const float* __restrict__ a_in, const float* __restrict__ M_in,
                        float* __restrict__ aP, float4* __restrict__ MpV,
                        int B, int K, int stride, int h, int w, int oh, int ow) {
    int P = oh*ow, KK = K*K, ni = B*KK;
    int idx = blockIdx.x * blockDim.x + threadIdx.x;
    if (idx >= 16*ni*P) return;
    int i = idx % ni, p = (idx/ni) % P, b = idx/(ni*P);
    int Bi = i / KK, kk = i % KK, ki = kk / K, kj = kk % K;
    int py = p / ow, px = p % ow;
    int src = (py*stride + ki)*w + (px*stride + kj);
    int hw = h*w;
    aP[idx] = a_in[(b*B + Bi)*hw + src];
    const float* Ms = M_in + (size_t)((b*B + Bi)*16)*hw + src;
    size_t base = (size_t)(b*P + p)*4;
    #pragma unroll
    for (int m4 = 0; m4 < 4; ++m4)
        MpV[(base + m4)*ni + i] = make_float4(Ms[(4*m4+0)*hw], Ms[(4*m4+1)*hw],
                                              Ms[(4*m4+2)*hw], Ms[(4*m4+3)*hw]);
}

// W transpose, m4-interleaved: WtV[(c*4+m4)*NI + i] = float4(W[(i*C+c)*16+4*m4..])
__global__ void k_wt(const float* __restrict__ W, float4* __restrict__ WtV,
                     int NI, int C) {
    int idx = blockIdx.x * blockDim.x + threadIdx.x;
    if (idx >= NI*C) return;
    int i = idx % NI, c = idx/NI;
    const float* src = W + (size_t)(i*C + c)*16;
    #pragma unroll
    for (int m4 = 0; m4 < 4; ++m4)
        WtV[((size_t)c*4 + m4)*NI + i] = make_float4(src[4*m4+0], src[4*m4+1],
                                                     src[4*m4+2], src[4*m4+3]);
}

// ---------------------------------------------------------------------------
// EM stats: 4 waves/block, wave w -> c = cg*4+w, shared (b,p) slice.
// EXPLICIT 1-deep software pipeline: preload it+1's operands while computing
// it (latency-bound fix; VGPR budget raised via waves_per_eu(4,8)).
// Clamped-index loads + multiplicative tail mask (no divergent loads).
// ---------------------------------------------------------------------------
template<int NI, int NJ, int P, int C>
__global__ __launch_bounds__(256) __attribute__((amdgpu_waves_per_eu(4,8)))
void k_stats(const float* __restrict__ aP, const float4* __restrict__ MpV,
             const float4* __restrict__ WtV, const float* __restrict__ svb,
             const float* __restrict__ mxs, const float* __restrict__ ism,
             const float* __restrict__ beta_a, const float* __restrict__ beta_u,
             float* __restrict__ statP,
             float* __restrict__ a_fin, float* __restrict__ M_fin,
             int t, float lam, int fin)
{
    constexpr int NIT = (NI + 63) / 64;
    constexpr int RS = 20;
    __shared__ float sRed[4][33*RS];    // 10.56 KB
    int wave = threadIdx.x >> 6, lane = threadIdx.x & 63;
    int g  = blockIdx.x % (16*P);
    int cg = blockIdx.x / (16*P);
    int c  = cg*4 + wave;
    int bb = g / P, p = g % P;
    int j  = c*P + p;

    const float*  aPb = aP  + (size_t)(bb*P + p)*NI;
    const float4* Mb  = MpV + (size_t)(bb*P + p)*4*NI;
    const float4* Wb  = WtV + (size_t)c*4*NI;
    const float*  svr = svb + (size_t)(bb*NJ + j)*NI;
    const float*  mxb = mxs + bb*NI;
    const float*  imb = ism + bb*NI;

    float accw = 0.f, accm[16], acc2[16];
    #pragma unroll
    for (int m = 0; m < 16; ++m) { accm[m] = 0.f; acc2[m] = 0.f; }

    // ---- pipeline prologue: load it=0 ----
    int iC = (lane < NI) ? lane : (NI-1);
    float4 mc0 = Mb[0*NI+iC], mc1 = Mb[1*NI+iC], mc2 = Mb[2*NI+iC], mc3 = Mb[3*NI+iC];
    float4 wc0 = Wb[0*NI+iC], wc1 = Wb[1*NI+iC], wc2 = Wb[2*NI+iC], wc3 = Wb[3*NI+iC];
    float apc = aPb[iC];
    float svc = 0.f, mxc = 0.f, imc = 0.f;
    if (t > 0) { svc = svr[iC]; mxc = mxb[iC]; imc = imb[iC]; }

    #pragma unroll
    for (int it = 0; it < NIT; ++it) {
        // ---- prefetch it+1 ----
        float4 mn0, mn1, mn2, mn3, wn0, wn1, wn2, wn3;
        float apn = 0.f, svn = 0.f, mxn = 0.f, imn = 0.f;
        if (it + 1 < NIT) {
            int i = lane + (it+1)*64;
            int iN = (i < NI) ? i : (NI-1);
            mn0 = Mb[0*NI+iN]; mn1 = Mb[1*NI+iN]; mn2 = Mb[2*NI+iN]; mn3 = Mb[3*NI+iN];
            wn0 = Wb[0*NI+iN]; wn1 = Wb[1*NI+iN]; wn2 = Wb[2*NI+iN]; wn3 = Wb[3*NI+iN];
            apn = aPb[iN];
            if (t > 0) { svn = svr[iN]; mxn = mxb[iN]; imn = imb[iN]; }
        }
        // ---- compute with current ----
        {
            int i = lane + it*64;
            float mask = ((NI % 64 == 0) || (i < NI)) ? 1.f : 0.f;
            float r = (t == 0) ? (1.f/NJ) : (__expf(svc - mxc) * imc);
            float wgt = r * apc * mask;
            accw += wgt;
            #pragma unroll
            for (int rr = 0; rr < 4; ++rr) {
                float4 w = (rr == 0) ? wc0 : (rr == 1) ? wc1 : (rr == 2) ? wc2 : wc3;
                float v0 = fmaf(w.w, mc3.x, fmaf(w.z, mc2.x, fmaf(w.y, mc1.x, w.x*mc0.x)));
                float v1 = fmaf(w.w, mc3.y, fmaf(w.z, mc2.y, fmaf(w.y, mc1.y, w.x*mc0.y)));
                float v2 = fmaf(w.w, mc3.z, fmaf(w.z, mc2.z, fmaf(w.y, mc1.z, w.x*mc0.z)));
                float v3 = fmaf(w.w, mc3.w, fmaf(w.z, mc2.w, fmaf(w.y, mc1.w, w.x*mc0.w)));
                float t0 = wgt*v0, t1 = wgt*v1, t2 = wgt*v2, t3 = wgt*v3;
                accm[rr*4+0] += t0; acc2[rr*4+0] = fmaf(t0, v0, acc2[rr*4+0]);
                accm[rr*4+1] += t1; acc2[rr*4+1] = fmaf(t1, v1, acc2[rr*4+1]);
                accm[rr*4+2] += t2; acc2[rr*4+2] = fmaf(t2, v2, acc2[rr*4+2]);
                accm[rr*4+3] += t3; acc2[rr*4+3] = fmaf(t3, v3, acc2[rr*4+3]);
            }
        }
        // ---- rotate ----
        if (it + 1 < NIT) {
            mc0 = mn0; mc1 = mn1; mc2 = mn2; mc3 = mn3;
            wc0 = wn0; wc1 = wn1; wc2 = wn2; wc3 = wn3;
            apc = apn; svc = svn; mxc = mxn; imc = imn;
        }
    }

    // 2-step shuffle pre-reduce (4-lane groups), then LDS transpose [value][group]
    accw += __shfl_xor(accw, 1); accw += __shfl_xor(accw, 2);
    #pragma unroll
    for (int m = 0; m < 16; ++m) {
        accm[m] += __shfl_xor(accm[m], 1); accm[m] += __shfl_xor(accm[m], 2);
        acc2[m] += __shfl_xor(acc2[m], 1); acc2[m] += __shfl_xor(acc2[m], 2);
    }
    float* row = sRed[wave];
    if ((lane & 3) == 0) {
        int grp = lane >> 2;
        row[0*RS + grp] = accw;
        #pragma unroll
        for (int m = 0; m < 16; ++m) {
            row[(1+m)*RS + grp]  = accm[m];
            row[(17+m)*RS + grp] = acc2[m];
        }
    }
    float S = 0.f;
    if (lane < 33) {
        const float4* r4 = (const float4*)(row + lane*RS);
        float4 a = r4[0], b4 = r4[1], c4 = r4[2], d4 = r4[3];
        S = (((a.x+a.y)+(a.z+a.w)) + ((b4.x+b4.y)+(b4.z+b4.w)))
          + (((c4.x+c4.y)+(c4.z+c4.w)) + ((d4.x+d4.y)+(d4.z+d4.w)));
    }
    float coeff = fmaxf(__shfl(S, 0), 1e-8f);
    float Sn = S / coeff;               // lanes 1..16: mu_m ; lanes 17..32: E[V^2]_m
    bool sig_lane = (lane >= 17 && lane < 33);
    int srcl = sig_lane ? (lane - 16) : 0;
    float muk = __shfl(Sn, srcl);       // mu_m on sigma lanes
    float lg = 0.f, iv = 0.f;
    if (sig_lane) {
        float s = fmaxf(Sn - muk*muk, 1e-8f);
        lg = __logf(s);
        iv = 1.f / s;
    }
    float v = sig_lane ? lg : 0.f;
    #pragma unroll
    for (int off = 1; off < 64; off <<= 1) v += __shfl_xor(v, off);
    float lsum = v;
    float ao = 1.f/(1.f + __expf(-(lam * (beta_a[j % C] - (16.f*beta_u[j % C] + 0.5f*lsum) * coeff))));
    float G = 0.f, H2 = 0.f, gmu2 = 0.f;
    if (sig_lane) {
        G = -0.5f*ao*iv;
        H2 = -2.f*G*muk;
        gmu2 = G*muk*muk;
    }
    float u = sig_lane ? gmu2 : 0.f;
    #pragma unroll
    for (int off = 1; off < 64; off <<= 1) u += __shfl_xor(u, off);
    float K1 = fmaf(-0.5f*ao, 16.f*LN2PI + lsum, u);

    float* st = statP + (size_t)(bb*NJ + j)*36;
    if (sig_lane) {
        st[lane-17]      = G;
        st[16 + lane-17] = H2;
    }
    if (lane == 0) st[32] = K1;
    if (fin) {
        if (lane == 0) a_fin[bb*NJ + j] = ao;
        if (lane >= 1 && lane < 17)
            M_fin[(size_t)(bb*16 + lane-1)*NJ + j] = Sn;   // mu, faithful scramble
    }
}

// ---------------------------------------------------------------------------
// k_sv (round-9 best): block = (b,p), lane = i. M register-resident; loop c,
// compute sv, online per-lane max/sum, coalesced svb writes; partials per p.
// ---------------------------------------------------------------------------
template<int NI, int NJ, int P, int C>
__global__ __launch_bounds__(320)
void k_sv(const float4* __restrict__ MpV, const float4* __restrict__ WtV,
          const float* __restrict__ statP,
          float* __restrict__ svb, float* __restrict__ pmx, float* __restrict__ psm)
{
    int p = blockIdx.x % P, bb = blockIdx.x / P;
    int i = threadIdx.x;
    bool act = (i < NI);

    float4 m0, m1, m2, m3;
    if (act) {
        const float4* Mb = MpV + (size_t)(bb*P + p)*4*NI;
        m0 = Mb[0*NI+i]; m1 = Mb[1*NI+i]; m2 = Mb[2*NI+i]; m3 = Mb[3*NI+i];
    }
    float mx = -3.0e38f, sm = 0.f;

    for (int c = 0; c < C; ++c) {
        int j = c*P + p;
        const float* st = statP + (size_t)(bb*NJ + j)*36;   // uniform -> s_loads
        if (act) {
            const float4* Wb = WtV + (size_t)c*4*NI;
            float4 w0 = Wb[0*NI+i], w1 = Wb[1*NI+i], w2 = Wb[2*NI+i], w3 = Wb[3*NI+i];
            float V[16];
            {
                float4 w = w0;
                V[0] = fmaf(w.w, m3.x, fmaf(w.z, m2.x, fmaf(w.y, m1.x, w.x*m0.x)));
                V[1] = fmaf(w.w, m3.y, fmaf(w.z, m2.y, fmaf(w.y, m1.y, w.x*m0.y)));
                V[2] = fmaf(w.w, m3.z, fmaf(w.z, m2.z, fmaf(w.y, m1.z, w.x*m0.z)));
                V[3] = fmaf(w.w, m3.w, fmaf(w.z, m2.w, fmaf(w.y, m1.w, w.x*m0.w)));
                w = w1;
                V[4] = fmaf(w.w, m3.x, fmaf(w.z, m2.x, fmaf(w.y, m1.x, w.x*m0.x)));
                V[5] = fmaf(w.w, m3.y, fmaf(w.z, m2.y, fmaf(w.y, m1.y, w.x*m0.y)));
                V[6] = fmaf(w.w, m3.z, fmaf(w.z, m2.z, fmaf(w.y, m1.z, w.x*m0.z)));
                V[7] = fmaf(w.w, m3.w, fmaf(w.z, m2.w, fmaf(w.y, m1.w, w.x*m0.w)));
                w = w2;
                V[8]  = fmaf(w.w, m3.x, fmaf(w.z, m2.x, fmaf(w.y, m1.x, w.x*m0.x)));
                V[9]  = fmaf(w.w, m3.y, fmaf(w.z, m2.y, fmaf(w.y, m1.y, w.x*m0.y)));
                V[10] = fmaf(w.w, m3.z, fmaf(w.z, m2.z, fmaf(w.y, m1.z, w.x*m0.z)));
                V[11] = fmaf(w.w, m3.w, fmaf(w.z, m2.w, fmaf(w.y, m1.w, w.x*m0.w)));
                w = w3;
                V[12] = fmaf(w.w, m3.x, fmaf(w.z, m2.x, fmaf(w.y, m1.x, w.x*m0.x)));
                V[13] = fmaf(w.w, m3.y, fmaf(w.z, m2.y, fmaf(w.y, m1.y, w.x*m0.y)));
                V[14] = fmaf(w.w, m3.z, fmaf(w.z, m2.z, fmaf(w.y, m1.z, w.x*m0.z)));
                V[15] = fmaf(w.w, m3.w, fmaf(w.z, m2.w, fmaf(w.y, m1.w, w.x*m0.w)));
            }
            float acc = 0.f;
            #pragma unroll
            for (int m = 0; m < 16; ++m) {
                float tmp = fmaf(V[m], st[m], st[16+m]);
                acc = fmaf(V[m], tmp, acc);
            }
            float sv = st[32] + acc;
            if (sv > mx) { sm = sm*__expf(mx - sv) + 1.f; mx = sv; }
            else         { sm += __expf(sv - mx); }
            svb[(size_t)(bb*NJ + j)*NI + i] = sv;
        }
    }
    if (act) {
        pmx[(size_t)p*(16*NI) + bb*NI + i] = mx;
        psm[(size_t)p*(16*NI) + bb*NI + i] = sm;
    }
}

// ---------------------------------------------------------------------------
// combine chunk partials -> mxs, ism (per (b,i))
// ---------------------------------------------------------------------------
__global__ void k_comb(const float* __restrict__ pmx, const float* __restrict__ psm,
                       float* __restrict__ mxs, float* __restrict__ ism,
                       int nch, int ntot)
{
    int idx = blockIdx.x * blockDim.x + threadIdx.x;
    if (idx >= ntot) return;
    float mx = -3.0e38f, sm = 0.f;
    for (int ch = 0; ch < nch; ++ch) {
        float m2 = pmx[(size_t)ch*ntot + idx];
        float s2 = psm[(size_t)ch*ntot + idx];
        float M = fmaxf(mx, m2);
        sm = sm*__expf(mx - M) + s2*__expf(m2 - M);
        mx = M;
    }
    mxs[idx] = mx;
    ism[idx] = 1.f / sm;
}

// ---------------------------------------------------------------------------
// layer 4 fused (verified): 512 thr; waves 0-4 own one j each.
// ---------------------------------------------------------------------------
__global__ __launch_bounds__(512)
void k_layer4(const float* __restrict__ a3, const float* __restrict__ M3,
              const float* __restrict__ W4, const float* __restrict__ ba4,
              const float* __restrict__ bu4, float* __restrict__ out)
{
    __shared__ float sMt[16*512];
    __shared__ float sA[512];
    __shared__ float sW[2560];
    __shared__ float sR[2560];
    __shared__ float sStat[5][34];

    int b = blockIdx.x, tid = threadIdx.x;
    int lane = tid & 63, wave = tid >> 6;

    for (int k = tid; k < 8192; k += 512) {
        int i = k & 511, m = k >> 9;
        sMt[k] = M3[b*8192 + (i & ~15)*16 + m*16 + (i & 15)];
    }
    sA[tid] = a3[b*512 + tid];
    for (int k = tid; k < 2560; k += 512) { sW[k] = W4[k]; sR[k] = 0.2f; }
    __syncthreads();

    const float lams[3] = {5.0e-4f, 9.75e-4f, 1.426250e-3f};

    for (int t = 0; t < 3; ++t) {
        if (wave < 5) {
            int j = wave;
            float accw = 0.f, accm[16], acc2[16];
            #pragma unroll
            for (int m = 0; m < 16; ++m) { accm[m] = 0.f; acc2[m] = 0.f; }
            for (int u = 0; u < 8; ++u) {
                int i = u*64 + lane;
                float wgt = sR[i*5 + j] * sA[i];
                float Mm[16];
                #pragma unroll
                for (int m = 0; m < 16; ++m) Mm[m] = sMt[m*512 + i];
                const float* Wm = &sW[((i>>4)*5 + j)*16];
                float V[16];
                #pragma unroll
                for (int r = 0; r < 4; ++r)
                    #pragma unroll
                    for (int cc = 0; cc < 4; ++cc) {
                        float s = Wm[r*4+0]*Mm[0*4+cc];
                        s = fmaf(Wm[r*4+1], Mm[1*4+cc], s);
                        s = fmaf(Wm[r*4+2], Mm[2*4+cc], s);
                        s = fmaf(Wm[r*4+3], Mm[3*4+cc], s);
                        V[r*4+cc] = s;
                    }
                V[0] += (float)((i & 15) >> 2) * 0.25f;
                V[1] += (float)(i & 3) * 0.25f;
                accw += wgt;
                #pragma unroll
                for (int m = 0; m < 16; ++m) {
                    float t1 = wgt * V[m];
                    accm[m] += t1;
                    acc2[m] = fmaf(t1, V[m], acc2[m]);
                }
            }
            for (int off = 1; off < 64; off <<= 1) {
                accw += __shfl_xor(accw, off);
                #pragma unroll
                for (int m = 0; m < 16; ++m) accm[m] += __shfl_xor(accm[m], off);
                #pragma unroll
                for (int m = 0; m < 16; ++m) acc2[m] += __shfl_xor(acc2[m], off);
            }
            float coeff = fmaxf(accw, 1e-8f);
            float lsum = 0.f, mu[16], isv[16];
            #pragma unroll
            for (int m = 0; m < 16; ++m) {
                mu[m] = accm[m] / coeff;
                float s = fmaxf(acc2[m]/coeff - mu[m]*mu[m], 1e-8f);
                lsum += __logf(s);
                isv[m] = 1.f / s;
            }
            float ao = 1.f/(1.f + __expf(-(lams[t] * (ba4[j] - (16.f*bu4[j] + 0.5f*lsum) * coeff))));
            if (lane == 0) {
                #pragma unroll
                for (int m = 0; m < 16; ++m) { sStat[j][m] = mu[m]; sStat[j][16+m] = isv[m]; }
                sStat[j][32] = lsum; sStat[j][33] = ao;
            }
        }
        __syncthreads();
        if (t < 2) {
            int i = tid;
            float Mm[16];
            #pragma unroll
            for (int m = 0; m < 16; ++m) Mm[m] = sMt[m*512 + i];
            float sv[5], mxv = -3.0e38f;
            #pragma unroll
            for (int j = 0; j < 5; ++j) {
                const float* Wm = &sW[((i>>4)*5 + j)*16];
                float V[16];
                #pragma unroll
                for (int r = 0; r < 4; ++r)
                    #pragma unroll
                    for (int cc = 0; cc < 4; ++cc) {
                        float s = Wm[r*4+0]*Mm[0*4+cc];
                        s = fmaf(Wm[r*4+1], Mm[1*4+cc], s);
                        s = fmaf(Wm[r*4+2], Mm[2*4+cc], s);
                        s = fmaf(Wm[r*4+3], Mm[3*4+cc], s);
                        V[r*4+cc] = s;
                    }
                V[0] += (float)((i & 15) >> 2) * 0.25f;
                V[1] += (float)(i & 3) * 0.25f;
                float q = 0.f;
                #pragma unroll
                for (int m = 0; m < 16; ++m) {
                    float d = V[m] - sStat[j][m];
                    q = fmaf(d*d, sStat[j][16+m], q);
                }
                float logp = -0.5f * (16.f*LN2PI + sStat[j][32] + q);
                sv[j] = sStat[j][33] * logp;
                mxv = fmaxf(mxv, sv[j]);
            }
            float sum = 0.f;
            #pragma unroll
            for (int j = 0; j < 5; ++j) { sv[j] = __expf(sv[j] - mxv); sum += sv[j]; }
            float inv = 1.f / sum;
            #pragma unroll
            for (int j = 0; j < 5; ++j) sR[i*5 + j] = sv[j] * inv;
            __syncthreads();
        }
    }
    if (tid < 5) out[b*5 + tid] = sStat[tid][33];
}

// ---------------------------------------------------------------------------
// host: one EM layer (layers 2/3)
// ---------------------------------------------------------------------------
template<int NI, int NJ, int P, int C>
static void run_em(hipStream_t stream,
                   const float* aP, const float4* MpV, const float4* WtV,
                   const float* ba, const float* bu,
                   float* statP, float* svb, float* mxs, float* ism,
                   float* pmx, float* psm,
                   float* a_fin, float* M_fin)
{
    const float lams[3] = {5.0e-4f, 9.75e-4f, 1.426250e-3f};
    for (int t = 0; t < 3; ++t) {
        k_stats<NI,NJ,P,C><<<16*NJ/4, 256, 0, stream>>>(
            aP, MpV, WtV, svb, mxs, ism, ba, bu, statP, a_fin, M_fin,
            t, lams[t], (t == 2) ? 1 : 0);
        if (t < 2) {
            k_sv<NI,NJ,P,C><<<16*P, 320, 0, stream>>>(MpV, WtV, statP, svb, pmx, psm);
            k_comb<<<(16*NI + 255)/256, 256, 0, stream>>>(pmx, psm, mxs, ism, P, 16*NI);
        }
    }
}

extern "C" void kernel_launch(void* const* d_in, const int* in_sizes, int n_in,
                              void* d_out, int out_size, void* d_ws, size_t ws_size,
                              hipStream_t stream) {
    (void)in_sizes; (void)n_in; (void)out_size; (void)ws_size;
    const float* x       = (const float*)d_in[0];
    const float* conv_w  = (const float*)d_in[1];
    const float* conv_b  = (const float*)d_in[2];
    const float* pose_w  = (const float*)d_in[3];
    const float* pose_b  = (const float*)d_in[4];
    const float* act_w   = (const float*)d_in[5];
    const float* act_b   = (const float*)d_in[6];
    const float* W2      = (const float*)d_in[7];
    const float* beta_a2 = (const float*)d_in[8];
    const float* beta_u2 = (const float*)d_in[9];
    const float* W3      = (const float*)d_in[10];
    const float* beta_a3 = (const float*)d_in[11];
    const float* beta_u3 = (const float*)d_in[12];
    const float* W4      = (const float*)d_in[13];
    const float* beta_a4 = (const float*)d_in[14];
    const float* beta_u4 = (const float*)d_in[15];

    // workspace layout (floats), ~47.5 MB total
    float* ws    = (float*)d_ws;
    float* fea   = ws;                    // 100352
    float* a1    = fea   + 100352;        // 100352
    float* M1    = a1    + 100352;        // 1605632
    float* aP    = M1    + 1605632;       // 165888 (max)
    float* Mp    = aP    + 165888;        // 2654208 (max, float4-aligned)
    float* Wt    = Mp    + 2654208;       // 147456
    float* statP = Wt    + 147456;        // 663552 (16*1152*36)
    float* svb   = statP + 663552;        // 5308416 (16*1152*288)
    float* mxs   = svb   + 5308416;       // 4608
    float* ismb  = mxs   + 4608;          // 4608
    float* pmx   = ismb  + 4608;          // 331776 (36*4608 max)
    float* psm   = pmx   + 331776;        // 331776
    float* a2    = psm   + 331776;        // 18432
    float* M2    = a2    + 18432;         // 294912
    float* a3    = M2    + 294912;        // 8192
    float* M3    = a3    + 8192;          // 131072

    float4* MpV = (float4*)Mp;
    float4* WtV = (float4*)Wt;

    // stem + primary caps
    k_stem<<<(16*32*196 + 255)/256, 256, 0, stream>>>(x, conv_w, conv_b, fea);
    k_primary<<<(16*544*196 + 255)/256, 256, 0, stream>>>(fea, pose_w, pose_b,
                                                          act_w, act_b, M1, a1);

    // layer 2: NI=288, NJ=1152, P=36, C=32
    k_patch<<<(16*288*36 + 255)/256, 256, 0, stream>>>(a1, M1, aP, MpV, 32, 3, 2, 14, 14, 6, 6);
    k_wt<<<(288*32 + 255)/256, 256, 0, stream>>>(W2, WtV, 288, 32);
    run_em<288,1152,36,32>(stream, aP, MpV, WtV, beta_a2, beta_u2,
                           statP, svb, mxs, ismb, pmx, psm, a2, M2);

    // layer 3: NI=288, NJ=512, P=16, C=32
    k_patch<<<(16*288*16 + 255)/256, 256, 0, stream>>>(a2, M2, aP, MpV, 32, 3, 1, 6, 6, 4, 4);
    k_wt<<<(288*32 + 255)/256, 256, 0, stream>>>(W3, WtV, 288, 32);
    run_em<288,512,16,32>(stream, aP, MpV, WtV, beta_a3, beta_u3,
                          statP, svb, mxs, ismb, pmx, psm, a3, M3);

    // layer 4 fused
    k_layer4<<<16, 512, 0, stream>>>(a3, M3, W4, beta_a4, beta_u4, (float*)d_out);
}

// Round 14
// 501.233 us; speedup vs baseline: 1.7625x; 1.7625x over previous
//
#include <hip/hip_runtime.h>
#include <math.h>

#define LN2PI 1.83787706640934548356f

// ---------------------------------------------------------------------------
// stem: conv 5x5 stride 2 valid + bias + relu : (16,2,32,32) -> (16,32,14,14)
// ---------------------------------------------------------------------------
__global__ void k_stem(const float* __restrict__ x, const float* __restrict__ w,
                       const float* __restrict__ bias, float* __restrict__ fea) {
    int idx = blockIdx.x * blockDim.x + threadIdx.x;
    if (idx >= 16*32*14*14) return;
    int ox = idx % 14, oy = (idx/14) % 14, oc = (idx/196) % 32, b = idx/(196*32);
    float s = bias[oc];
    const float* xb = x + b*2*1024;
    const float* wc = w + oc*2*25;
    #pragma unroll
    for (int ic = 0; ic < 2; ++ic)
        #pragma unroll
        for (int ky = 0; ky < 5; ++ky)
            #pragma unroll
            for (int kx = 0; kx < 5; ++kx)
                s = fmaf(xb[ic*1024 + (oy*2+ky)*32 + (ox*2+kx)],
                         wc[ic*25 + ky*5 + kx], s);
    fea[idx] = fmaxf(s, 0.f);
}

// ---------------------------------------------------------------------------
// primary caps
// ---------------------------------------------------------------------------
__global__ void k_primary(const float* __restrict__ fea,
                          const float* __restrict__ pw, const float* __restrict__ pb,
                          const float* __restrict__ aw, const float* __restrict__ ab,
                          float* __restrict__ M, float* __restrict__ a) {
    int idx = blockIdx.x * blockDim.x + threadIdx.x;
    if (idx >= 16*544*196) return;
    int hw = idx % 196, o = (idx/196) % 544, b = idx/(196*544);
    const float* f = fea + b*32*196 + hw;
    if (o < 512) {
        float s = pb[o];
        #pragma unroll
        for (int c = 0; c < 32; ++c) s = fmaf(f[c*196], pw[o*32+c], s);
        M[(b*512+o)*196 + hw] = s;
    } else {
        int oo = o - 512;
        float s = ab[oo];
        #pragma unroll
        for (int c = 0; c < 32; ++c) s = fmaf(f[c*196], aw[oo*32+c], s);
        a[(b*32+oo)*196 + hw] = 1.f/(1.f + __expf(-s));
    }
}

// ---------------------------------------------------------------------------
// patch extraction, m4-interleaved: aP[(b*P+p)*NI + i],
// MpV[((b*P+p)*4 + m4)*NI + i] = float4 of pose rows (coalesced per-lane-i)
// ---------------------------------------------------------------------------
__global__ void k_patch(const float* __restrict__ a_in, const float* __restrict__ M_in,
                        float* __restrict__ aP, float4* __restrict__ MpV,
                        int B, int K, int stride, int h, int w, int oh, int ow) {
    int P = oh*ow, KK = K*K, ni = B*KK;
    int idx = blockIdx.x * blockDim.x + threadIdx.x;
    if (idx >= 16*ni*P) return;
    int i = idx % ni, p = (idx/ni) % P, b = idx/(ni*P);
    int Bi = i / KK, kk = i % KK, ki = kk / K, kj = kk % K;
    int py = p / ow, px = p % ow;
    int src = (py*stride + ki)*w + (px*stride + kj);
    int hw = h*w;
    aP[idx] = a_in[(b*B + Bi)*hw + src];
    const float* Ms = M_in + (size_t)((b*B + Bi)*16)*hw + src;
    size_t base = (size_t)(b*P + p)*4;
    #pragma unroll
    for (int m4 = 0; m4 < 4; ++m4)
        MpV[(base + m4)*ni + i] = make_float4(Ms[(4*m4+0)*hw], Ms[(4*m4+1)*hw],
                                              Ms[(4*m4+2)*hw], Ms[(4*m4+3)*hw]);
}

// W transpose, m4-interleaved: WtV[(c*4+m4)*NI + i] = float4(W[(i*C+c)*16+4*m4..])
__global__ void k_wt(const float* __restrict__ W, float4* __restrict__ WtV,
                     int NI, int C) {
    int idx = blockIdx.x * blockDim.x + threadIdx.x;
    if (idx >= NI*C) return;
    int i = idx % NI, c = idx/NI;
    const float* src = W + (size_t)(i*C + c)*16;
    #pragma unroll
    for (int m4 = 0; m4 < 4; ++m4)
        WtV[((size_t)c*4 + m4)*NI + i] = make_float4(src[4*m4+0], src[4*m4+1],
                                                     src[4*m4+2], src[4*m4+3]);
}

// ---------------------------------------------------------------------------
// EM stats: 4 waves/block, wave w -> c = cg*4+w, shared (b,p) slice.
// waves_per_eu(4,4): pins allocator target to 4 waves/EU -> VGPR budget 128,
// letting the compiler hoist the fully-unrolled i-loop's loads (latency fix).
// 2-step shuffle pre-reduce -> small LDS transpose. Packed stats G/H2/K1.
// ---------------------------------------------------------------------------
template<int NI, int NJ, int P, int C>
__global__ __launch_bounds__(256) __attribute__((amdgpu_waves_per_eu(4,4)))
void k_stats(const float* __restrict__ aP, const float4* __restrict__ MpV,
             const float4* __restrict__ WtV, const float* __restrict__ svb,
             const float* __restrict__ mxs, const float* __restrict__ ism,
             const float* __restrict__ beta_a, const float* __restrict__ beta_u,
             float* __restrict__ statP,
             float* __restrict__ a_fin, float* __restrict__ M_fin,
             int t, float lam, int fin)
{
    constexpr int NIT = (NI + 63) / 64;
    constexpr int RS = 20;              // 16 group-sums + pad, 16B-aligned rows
    __shared__ float sRed[4][33*RS];    // 10.56 KB
    int wave = threadIdx.x >> 6, lane = threadIdx.x & 63;
    int g  = blockIdx.x % (16*P);
    int cg = blockIdx.x / (16*P);
    int c  = cg*4 + wave;
    int bb = g / P, p = g % P;
    int j  = c*P + p;

    const float*  aPb = aP  + (size_t)(bb*P + p)*NI;
    const float4* Mb  = MpV + (size_t)(bb*P + p)*4*NI;
    const float4* Wb  = WtV + (size_t)c*4*NI;
    const float*  svr = svb + (size_t)(bb*NJ + j)*NI;
    const float*  mxb = mxs + bb*NI;
    const float*  imb = ism + bb*NI;

    float accw = 0.f, accm[16], acc2[16];
    #pragma unroll
    for (int m = 0; m < 16; ++m) { accm[m] = 0.f; acc2[m] = 0.f; }

    #pragma unroll
    for (int it = 0; it < NIT; ++it) {
        int i = lane + it*64;
        if ((NI % 64 == 0) || (i < NI)) {
            float r;
            if (t == 0) r = 1.f / NJ;
            else        r = __expf(svr[i] - mxb[i]) * imb[i];
            float wgt = r * aPb[i];
            float4 m0 = Mb[0*NI + i], m1 = Mb[1*NI + i];
            float4 m2 = Mb[2*NI + i], m3 = Mb[3*NI + i];
            accw += wgt;
            #pragma unroll
            for (int rr = 0; rr < 4; ++rr) {
                float4 w = Wb[rr*NI + i];
                float v0 = fmaf(w.w, m3.x, fmaf(w.z, m2.x, fmaf(w.y, m1.x, w.x*m0.x)));
                float v1 = fmaf(w.w, m3.y, fmaf(w.z, m2.y, fmaf(w.y, m1.y, w.x*m0.y)));
                float v2 = fmaf(w.w, m3.z, fmaf(w.z, m2.z, fmaf(w.y, m1.z, w.x*m0.z)));
                float v3 = fmaf(w.w, m3.w, fmaf(w.z, m2.w, fmaf(w.y, m1.w, w.x*m0.w)));
                float t0 = wgt*v0, t1 = wgt*v1, t2 = wgt*v2, t3 = wgt*v3;
                accm[rr*4+0] += t0; acc2[rr*4+0] = fmaf(t0, v0, acc2[rr*4+0]);
                accm[rr*4+1] += t1; acc2[rr*4+1] = fmaf(t1, v1, acc2[rr*4+1]);
                accm[rr*4+2] += t2; acc2[rr*4+2] = fmaf(t2, v2, acc2[rr*4+2]);
                accm[rr*4+3] += t3; acc2[rr*4+3] = fmaf(t3, v3, acc2[rr*4+3]);
            }
        }
    }

    // 2-step shuffle pre-reduce (4-lane groups), then LDS transpose [value][group]
    accw += __shfl_xor(accw, 1); accw += __shfl_xor(accw, 2);
    #pragma unroll
    for (int m = 0; m < 16; ++m) {
        accm[m] += __shfl_xor(accm[m], 1); accm[m] += __shfl_xor(accm[m], 2);
        acc2[m] += __shfl_xor(acc2[m], 1); acc2[m] += __shfl_xor(acc2[m], 2);
    }
    float* row = sRed[wave];
    if ((lane & 3) == 0) {
        int grp = lane >> 2;
        row[0*RS + grp] = accw;
        #pragma unroll
        for (int m = 0; m < 16; ++m) {
            row[(1+m)*RS + grp]  = accm[m];
            row[(17+m)*RS + grp] = acc2[m];
        }
    }
    float S = 0.f;
    if (lane < 33) {
        const float4* r4 = (const float4*)(row + lane*RS);
        float4 a = r4[0], b4 = r4[1], c4 = r4[2], d4 = r4[3];
        S = (((a.x+a.y)+(a.z+a.w)) + ((b4.x+b4.y)+(b4.z+b4.w)))
          + (((c4.x+c4.y)+(c4.z+c4.w)) + ((d4.x+d4.y)+(d4.z+d4.w)));
    }
    float coeff = fmaxf(__shfl(S, 0), 1e-8f);
    float Sn = S / coeff;               // lanes 1..16: mu_m ; lanes 17..32: E[V^2]_m
    bool sig_lane = (lane >= 17 && lane < 33);
    int srcl = sig_lane ? (lane - 16) : 0;
    float muk = __shfl(Sn, srcl);       // mu_m on sigma lanes
    float lg = 0.f, iv = 0.f;
    if (sig_lane) {
        float s = fmaxf(Sn - muk*muk, 1e-8f);
        lg = __logf(s);
        iv = 1.f / s;
    }
    float v = sig_lane ? lg : 0.f;
    #pragma unroll
    for (int off = 1; off < 64; off <<= 1) v += __shfl_xor(v, off);
    float lsum = v;
    float ao = 1.f/(1.f + __expf(-(lam * (beta_a[j % C] - (16.f*beta_u[j % C] + 0.5f*lsum) * coeff))));
    float G = 0.f, H2 = 0.f, gmu2 = 0.f;
    if (sig_lane) {
        G = -0.5f*ao*iv;
        H2 = -2.f*G*muk;
        gmu2 = G*muk*muk;
    }
    float u = sig_lane ? gmu2 : 0.f;
    #pragma unroll
    for (int off = 1; off < 64; off <<= 1) u += __shfl_xor(u, off);
    float K1 = fmaf(-0.5f*ao, 16.f*LN2PI + lsum, u);

    float* st = statP + (size_t)(bb*NJ + j)*36;
    if (sig_lane) {
        st[lane-17]      = G;
        st[16 + lane-17] = H2;
    }
    if (lane == 0) st[32] = K1;
    if (fin) {
        if (lane == 0) a_fin[bb*NJ + j] = ao;
        if (lane >= 1 && lane < 17)
            M_fin[(size_t)(bb*16 + lane-1)*NJ + j] = Sn;   // mu, faithful scramble
    }
}

// ---------------------------------------------------------------------------
// k_sv (round-9 best): block = (b,p), lane = i. M register-resident; loop c,
// compute sv, online per-lane max/sum, coalesced svb writes; partials per p.
// ---------------------------------------------------------------------------
template<int NI, int NJ, int P, int C>
__global__ __launch_bounds__(320)
void k_sv(const float4* __restrict__ MpV, const float4* __restrict__ WtV,
          const float* __restrict__ statP,
          float* __restrict__ svb, float* __restrict__ pmx, float* __restrict__ psm)
{
    int p = blockIdx.x % P, bb = blockIdx.x / P;
    int i = threadIdx.x;
    bool act = (i < NI);

    float4 m0, m1, m2, m3;
    if (act) {
        const float4* Mb = MpV + (size_t)(bb*P + p)*4*NI;
        m0 = Mb[0*NI+i]; m1 = Mb[1*NI+i]; m2 = Mb[2*NI+i]; m3 = Mb[3*NI+i];
    }
    float mx = -3.0e38f, sm = 0.f;

    for (int c = 0; c < C; ++c) {
        int j = c*P + p;
        const float* st = statP + (size_t)(bb*NJ + j)*36;   // uniform -> s_loads
        if (act) {
            const float4* Wb = WtV + (size_t)c*4*NI;
            float4 w0 = Wb[0*NI+i], w1 = Wb[1*NI+i], w2 = Wb[2*NI+i], w3 = Wb[3*NI+i];
            float V[16];
            {
                float4 w = w0;
                V[0] = fmaf(w.w, m3.x, fmaf(w.z, m2.x, fmaf(w.y, m1.x, w.x*m0.x)));
                V[1] = fmaf(w.w, m3.y, fmaf(w.z, m2.y, fmaf(w.y, m1.y, w.x*m0.y)));
                V[2] = fmaf(w.w, m3.z, fmaf(w.z, m2.z, fmaf(w.y, m1.z, w.x*m0.z)));
                V[3] = fmaf(w.w, m3.w, fmaf(w.z, m2.w, fmaf(w.y, m1.w, w.x*m0.w)));
                w = w1;
                V[4] = fmaf(w.w, m3.x, fmaf(w.z, m2.x, fmaf(w.y, m1.x, w.x*m0.x)));
                V[5] = fmaf(w.w, m3.y, fmaf(w.z, m2.y, fmaf(w.y, m1.y, w.x*m0.y)));
                V[6] = fmaf(w.w, m3.z, fmaf(w.z, m2.z, fmaf(w.y, m1.z, w.x*m0.z)));
                V[7] = fmaf(w.w, m3.w, fmaf(w.z, m2.w, fmaf(w.y, m1.w, w.x*m0.w)));
                w = w2;
                V[8]  = fmaf(w.w, m3.x, fmaf(w.z, m2.x, fmaf(w.y, m1.x, w.x*m0.x)));
                V[9]  = fmaf(w.w, m3.y, fmaf(w.z, m2.y, fmaf(w.y, m1.y, w.x*m0.y)));
                V[10] = fmaf(w.w, m3.z, fmaf(w.z, m2.z, fmaf(w.y, m1.z, w.x*m0.z)));
                V[11] = fmaf(w.w, m3.w, fmaf(w.z, m2.w, fmaf(w.y, m1.w, w.x*m0.w)));
                w = w3;
                V[12] = fmaf(w.w, m3.x, fmaf(w.z, m2.x, fmaf(w.y, m1.x, w.x*m0.x)));
                V[13] = fmaf(w.w, m3.y, fmaf(w.z, m2.y, fmaf(w.y, m1.y, w.x*m0.y)));
                V[14] = fmaf(w.w, m3.z, fmaf(w.z, m2.z, fmaf(w.y, m1.z, w.x*m0.z)));
                V[15] = fmaf(w.w, m3.w, fmaf(w.z, m2.w, fmaf(w.y, m1.w, w.x*m0.w)));
            }
            float acc = 0.f;
            #pragma unroll
            for (int m = 0; m < 16; ++m) {
                float tmp = fmaf(V[m], st[m], st[16+m]);
                acc = fmaf(V[m], tmp, acc);
            }
            float sv = st[32] + acc;
            if (sv > mx) { sm = sm*__expf(mx - sv) + 1.f; mx = sv; }
            else         { sm += __expf(sv - mx); }
            svb[(size_t)(bb*NJ + j)*NI + i] = sv;
        }
    }
    if (act) {
        pmx[(size_t)p*(16*NI) + bb*NI + i] = mx;
        psm[(size_t)p*(16*NI) + bb*NI + i] = sm;
    }
}

// ---------------------------------------------------------------------------
// combine chunk partials -> mxs, ism (per (b,i))
// ---------------------------------------------------------------------------
__global__ void k_comb(const float* __restrict__ pmx, const float* __restrict__ psm,
                       float* __restrict__ mxs, float* __restrict__ ism,
                       int nch, int ntot)
{
    int idx = blockIdx.x * blockDim.x + threadIdx.x;
    if (idx >= ntot) return;
    float mx = -3.0e38f, sm = 0.f;
    for (int ch = 0; ch < nch; ++ch) {
        float m2 = pmx[(size_t)ch*ntot + idx];
        float s2 = psm[(size_t)ch*ntot + idx];
        float M = fmaxf(mx, m2);
        sm = sm*__expf(mx - M) + s2*__expf(m2 - M);
        mx = M;
    }
    mxs[idx] = mx;
    ism[idx] = 1.f / sm;
}

// ---------------------------------------------------------------------------
// layer 4 fused (verified): 512 thr; waves 0-4 own one j each.
// ---------------------------------------------------------------------------
__global__ __launch_bounds__(512)
void k_layer4(const float* __restrict__ a3, const float* __restrict__ M3,
              const float* __restrict__ W4, const float* __restrict__ ba4,
              const float* __restrict__ bu4, float* __restrict__ out)
{
    __shared__ float sMt[16*512];
    __shared__ float sA[512];
    __shared__ float sW[2560];
    __shared__ float sR[2560];
    __shared__ float sStat[5][34];

    int b = blockIdx.x, tid = threadIdx.x;
    int lane = tid & 63, wave = tid >> 6;

    for (int k = tid; k < 8192; k += 512) {
        int i = k & 511, m = k >> 9;
        sMt[k] = M3[b*8192 + (i & ~15)*16 + m*16 + (i & 15)];
    }
    sA[tid] = a3[b*512 + tid];
    for (int k = tid; k < 2560; k += 512) { sW[k] = W4[k]; sR[k] = 0.2f; }
    __syncthreads();

    const float lams[3] = {5.0e-4f, 9.75e-4f, 1.426250e-3f};

    for (int t = 0; t < 3; ++t) {
        if (wave < 5) {
            int j = wave;
            float accw = 0.f, accm[16], acc2[16];
            #pragma unroll
            for (int m = 0; m < 16; ++m) { accm[m] = 0.f; acc2[m] = 0.f; }
            for (int u = 0; u < 8; ++u) {
                int i = u*64 + lane;
                float wgt = sR[i*5 + j] * sA[i];
                float Mm[16];
                #pragma unroll
                for (int m = 0; m < 16; ++m) Mm[m] = sMt[m*512 + i];
                const float* Wm = &sW[((i>>4)*5 + j)*16];
                float V[16];
                #pragma unroll
                for (int r = 0; r < 4; ++r)
                    #pragma unroll
                    for (int cc = 0; cc < 4; ++cc) {
                        float s = Wm[r*4+0]*Mm[0*4+cc];
                        s = fmaf(Wm[r*4+1], Mm[1*4+cc], s);
                        s = fmaf(Wm[r*4+2], Mm[2*4+cc], s);
                        s = fmaf(Wm[r*4+3], Mm[3*4+cc], s);
                        V[r*4+cc] = s;
                    }
                V[0] += (float)((i & 15) >> 2) * 0.25f;
                V[1] += (float)(i & 3) * 0.25f;
                accw += wgt;
                #pragma unroll
                for (int m = 0; m < 16; ++m) {
                    float t1 = wgt * V[m];
                    accm[m] += t1;
                    acc2[m] = fmaf(t1, V[m], acc2[m]);
                }
            }
            for (int off = 1; off < 64; off <<= 1) {
                accw += __shfl_xor(accw, off);
                #pragma unroll
                for (int m = 0; m < 16; ++m) accm[m] += __shfl_xor(accm[m], off);
                #pragma unroll
                for (int m = 0; m < 16; ++m) acc2[m] += __shfl_xor(acc2[m], off);
            }
            float coeff = fmaxf(accw, 1e-8f);
            float lsum = 0.f, mu[16], isv[16];
            #pragma unroll
            for (int m = 0; m < 16; ++m) {
                mu[m] = accm[m] / coeff;
                float s = fmaxf(acc2[m]/coeff - mu[m]*mu[m], 1e-8f);
                lsum += __logf(s);
                isv[m] = 1.f / s;
            }
            float ao = 1.f/(1.f + __expf(-(lams[t] * (ba4[j] - (16.f*bu4[j] + 0.5f*lsum) * coeff))));
            if (lane == 0) {
                #pragma unroll
                for (int m = 0; m < 16; ++m) { sStat[j][m] = mu[m]; sStat[j][16+m] = isv[m]; }
                sStat[j][32] = lsum; sStat[j][33] = ao;
            }
        }
        __syncthreads();
        if (t < 2) {
            int i = tid;
            float Mm[16];
            #pragma unroll
            for (int m = 0; m < 16; ++m) Mm[m] = sMt[m*512 + i];
            float sv[5], mxv = -3.0e38f;
            #pragma unroll
            for (int j = 0; j < 5; ++j) {
                const float* Wm = &sW[((i>>4)*5 + j)*16];
                float V[16];
                #pragma unroll
                for (int r = 0; r < 4; ++r)
                    #pragma unroll
                    for (int cc = 0; cc < 4; ++cc) {
                        float s = Wm[r*4+0]*Mm[0*4+cc];
                        s = fmaf(Wm[r*4+1], Mm[1*4+cc], s);
                        s = fmaf(Wm[r*4+2], Mm[2*4+cc], s);
                        s = fmaf(Wm[r*4+3], Mm[3*4+cc], s);
                        V[r*4+cc] = s;
                    }
                V[0] += (float)((i & 15) >> 2) * 0.25f;
                V[1] += (float)(i & 3) * 0.25f;
                float q = 0.f;
                #pragma unroll
                for (int m = 0; m < 16; ++m) {
                    float d = V[m] - sStat[j][m];
                    q = fmaf(d*d, sStat[j][16+m], q);
                }
                float logp = -0.5f * (16.f*LN2PI + sStat[j][32] + q);
                sv[j] = sStat[j][33] * logp;
                mxv = fmaxf(mxv, sv[j]);
            }
            float sum = 0.f;
            #pragma unroll
            for (int j = 0; j < 5; ++j) { sv[j] = __expf(sv[j] - mxv); sum += sv[j]; }
            float inv = 1.f / sum;
            #pragma unroll
            for (int j = 0; j < 5; ++j) sR[i*5 + j] = sv[j] * inv;
            __syncthreads();
        }
    }
    if (tid < 5) out[b*5 + tid] = sStat[tid][33];
}

// ---------------------------------------------------------------------------
// host: one EM layer (layers 2/3)
// ---------------------------------------------------------------------------
template<int NI, int NJ, int P, int C>
static void run_em(hipStream_t stream,
                   const float* aP, const float4* MpV, const float4* WtV,
                   const float* ba, const float* bu,
                   float* statP, float* svb, float* mxs, float* ism,
                   float* pmx, float* psm,
                   float* a_fin, float* M_fin)
{
    const float lams[3] = {5.0e-4f, 9.75e-4f, 1.426250e-3f};
    for (int t = 0; t < 3; ++t) {
        k_stats<NI,NJ,P,C><<<16*NJ/4, 256, 0, stream>>>(
            aP, MpV, WtV, svb, mxs, ism, ba, bu, statP, a_fin, M_fin,
            t, lams[t], (t == 2) ? 1 : 0);
        if (t < 2) {
            k_sv<NI,NJ,P,C><<<16*P, 320, 0, stream>>>(MpV, WtV, statP, svb, pmx, psm);
            k_comb<<<(16*NI + 255)/256, 256, 0, stream>>>(pmx, psm, mxs, ism, P, 16*NI);
        }
    }
}

extern "C" void kernel_launch(void* const* d_in, const int* in_sizes, int n_in,
                              void* d_out, int out_size, void* d_ws, size_t ws_size,
                              hipStream_t stream) {
    (void)in_sizes; (void)n_in; (void)out_size; (void)ws_size;
    const float* x       = (const float*)d_in[0];
    const float* conv_w  = (const float*)d_in[1];
    const float* conv_b  = (const float*)d_in[2];
    const float* pose_w  = (const float*)d_in[3];
    const float* pose_b  = (const float*)d_in[4];
    const float* act_w   = (const float*)d_in[5];
    const float* act_b   = (const float*)d_in[6];
    const float* W2      = (const float*)d_in[7];
    const float* beta_a2 = (const float*)d_in[8];
    const float* beta_u2 = (const float*)d_in[9];
    const float* W3      = (const float*)d_in[10];
    const float* beta_a3 = (const float*)d_in[11];
    const float* beta_u3 = (const float*)d_in[12];
    const float* W4      = (const float*)d_in[13];
    const float* beta_a4 = (const float*)d_in[14];
    const float* beta_u4 = (const float*)d_in[15];

    // workspace layout (floats), ~47.5 MB total
    float* ws    = (float*)d_ws;
    float* fea   = ws;                    // 100352
    float* a1    = fea   + 100352;        // 100352
    float* M1    = a1    + 100352;        // 1605632
    float* aP    = M1    + 1605632;       // 165888 (max)
    float* Mp    = aP    + 165888;        // 2654208 (max, float4-aligned)
    float* Wt    = Mp    + 2654208;       // 147456
    float* statP = Wt    + 147456;        // 663552 (16*1152*36)
    float* svb   = statP + 663552;        // 5308416 (16*1152*288)
    float* mxs   = svb   + 5308416;       // 4608
    float* ismb  = mxs   + 4608;          // 4608
    float* pmx   = ismb  + 4608;          // 331776 (36*4608 max)
    float* psm   = pmx   + 331776;        // 331776
    float* a2    = psm   + 331776;        // 18432
    float* M2    = a2    + 18432;         // 294912
    float* a3    = M2    + 294912;        // 8192
    float* M3    = a3    + 8192;          // 131072

    float4* MpV = (float4*)Mp;
    float4* WtV = (float4*)Wt;

    // stem + primary caps
    k_stem<<<(16*32*196 + 255)/256, 256, 0, stream>>>(x, conv_w, conv_b, fea);
    k_primary<<<(16*544*196 + 255)/256, 256, 0, stream>>>(fea, pose_w, pose_b,
                                                          act_w, act_b, M1, a1);

    // layer 2: NI=288, NJ=1152, P=36, C=32
    k_patch<<<(16*288*36 + 255)/256, 256, 0, stream>>>(a1, M1, aP, MpV, 32, 3, 2, 14, 14, 6, 6);
    k_wt<<<(288*32 + 255)/256, 256, 0, stream>>>(W2, WtV, 288, 32);
    run_em<288,1152,36,32>(stream, aP, MpV, WtV, beta_a2, beta_u2,
                           statP, svb, mxs, ismb, pmx, psm, a2, M2);

    // layer 3: NI=288, NJ=512, P=16, C=32
    k_patch<<<(16*288*16 + 255)/256, 256, 0, stream>>>(a2, M2, aP, MpV, 32, 3, 1, 6, 6, 4, 4);
    k_wt<<<(288*32 + 255)/256, 256, 0, stream>>>(W3, WtV, 288, 32);
    run_em<288,512,16,32>(stream, aP, MpV, WtV, beta_a3, beta_u3,
                          statP, svb, mxs, ismb, pmx, psm, a3, M3);

    // layer 4 fused
    k_layer4<<<16, 512, 0, stream>>>(a3, M3, W4, beta_a4, beta_u4, (float*)d_out);
}